// Round 1
// 128.901 us; speedup vs baseline: 1.0186x; 1.0186x over previous
//
#include <hip/hip_runtime.h>
#include <hip/hip_bf16.h>

// Flash-attention fwd, block-causal packed docs. fp32 HBM, bf16 MFMA.
// B=1, H=8, D=128. 4 waves/block, BR=64, BC=64, grid 512, 2 blocks/CU.
// R10: swapped-operand QK^T (S^T = K*Q^T, K as MFMA A-operand): each lane
// owns ONE query column -> softmax max = in-lane tree + 2 shfl_xor (was 16
// sequential shfl steps); m/l are per-lane scalars.
// P never leaves registers: PV computed as O^T = V^T * P^T with a
// key-permuted sVT layout chosen so the lane's own 16 p-values ARE the
// B-fragment (removes sP + 16 ds_write_u16 + lgkm drain + reload entirely).
// sVT: VSTR 33->36 (16B-aligned rows): reads 64x b32 -> 16x b128,
// staging writes 16x b32 -> 4x b128 (both uniform over 8 start-bank
// classes = conflict-free for wave64 b128). LDS 77312 -> 71680 B.
// Keeps: R7 register-prefetch pipeline + double-buffered LDS + 1 barrier/tile,
// R9 balanced qb pairing. Adds s_setprio(1) around MFMA clusters.

#define HD 128
#define BR 64
#define BC 64
#define KSTR 136     // bf16 per sK row: 272 B (b128-aligned, 8 uniform bank classes)
#define VSTR 36      // dwords per sVT row: 32 data + 4 pad = 144 B (16B-aligned)

typedef __attribute__((ext_vector_type(8))) short short8;
typedef __attribute__((ext_vector_type(4))) float floatx4;

__device__ inline unsigned packbf2(float lo, float hi) {
    __hip_bfloat162 h2 = __float22bfloat162_rn(make_float2(lo, hi));
    return *reinterpret_cast<unsigned*>(&h2);   // low16 = lo, high16 = hi
}
__device__ inline short bfs(float f) {
    __hip_bfloat16 b = __float2bfloat16(f);
    return *reinterpret_cast<short*>(&b);
}

union F4 { float4 v; float f[4]; };

__global__ __launch_bounds__(256, 2) void fa_fwd(
    const float* __restrict__ Q,
    const float* __restrict__ K,
    const float* __restrict__ V,
    const int* __restrict__ cu_seqlens, int n_cu,
    float* __restrict__ O,
    int S)
{
    __shared__ alignas(16) __hip_bfloat16 sK[2][BC * KSTR];   // 34816 B
    __shared__ alignas(16) unsigned int   sVT[2][HD * VSTR];  // 36864 B

    const int tid  = threadIdx.x;
    const int wave = tid >> 6;
    const int lane = tid & 63;
    const int quad = lane >> 4;
    const int l16  = lane & 15;

    // K staging coords
    const int dblk = tid & 31;      // d = 4*dblk
    const int trow = tid >> 5;      // 0..7
    // V staging coords: one d-row per thread
    const int vd    = tid & 127;
    const int vhalf = tid >> 7;

    const int nqb = S / BR;
    const int h   = blockIdx.x & 7;
    const int g   = (int)(blockIdx.x >> 3);   // 0..nqb-1
    int qb;
    if (nqb == 64) {
        // balanced pairing: (g, g+32) ntiles sum to 17
        if (g < 32) qb = (g >> 4) * 16 + (15 - (g & 15));        // docs 0,1 desc
        else        qb = 32 + (((g - 32) >> 4) * 16) + (g & 15); // docs 2,3 asc
    } else {
        qb = nqb - 1 - g;
    }
    const int q0    = qb * BR;
    const int qw    = q0 + wave * 16;
    const int qlane = qw + l16;     // the ONE query this lane owns

    const size_t hoff = (size_t)h * S * HD;
    const float* Qh = Q + hoff;
    const float* Kh = K + hoff;
    const float* Vh = V + hoff;
    float*       Oh = O + hoff;

    // ---- per-lane doc start ----
    int ds_lane = 0;
    for (int i = 0; i < n_cu; ++i) {
        int c = cu_seqlens[i];
        if (c <= qlane) ds_lane = c;
    }
    int blk_ds = 0;
    for (int i = 0; i < n_cu; ++i) {
        int c = cu_seqlens[i];
        if (c <= q0) blk_ds = c;
    }
    const int k_begin = blk_ds & ~(BC - 1);
    const int ntiles  = (q0 + BR - 1 - k_begin) / BC + 1;   // block-uniform

    // ---- Q fragments (B-operand: lane holds Q[qlane][ks*32 + quad*8 + j]) ----
    short8 aq[4];
    {
        const float* qp = Qh + (size_t)qlane * HD + quad * 8;
        #pragma unroll
        for (int ks = 0; ks < 4; ++ks) {
            float4 a0 = *(const float4*)(qp + ks * 32);
            float4 a1 = *(const float4*)(qp + ks * 32 + 4);
            short8 a;
            a[0] = bfs(a0.x); a[1] = bfs(a0.y); a[2] = bfs(a0.z); a[3] = bfs(a0.w);
            a[4] = bfs(a1.x); a[5] = bfs(a1.y); a[6] = bfs(a1.z); a[7] = bfs(a1.w);
            aq[ks] = a;
        }
    }

    // oacc[dt][r] = O[qlane][dt*16 + quad*4 + r]  (O^T layout: col=q, row=d)
    floatx4 oacc[8];
    #pragma unroll
    for (int dt = 0; dt < 8; ++dt) oacc[dt] = (floatx4){0.f, 0.f, 0.f, 0.f};
    float m_r = -1e30f, l_r = 0.f;   // per-lane scalars now

    const float sl = 0.08838834764831845f * 1.4426950408889634f;

    // ---- pipeline registers ----
    F4 kf[8];
    float vf[32];

    auto issue_loads = [&](int kt) {
        const float* kb = Kh + (size_t)kt * HD + 4 * dblk;
        #pragma unroll
        for (int p = 0; p < 8; ++p)
            kf[p].v = *(const float4*)(kb + (size_t)(trow + 8 * p) * HD);
        const float* vb = Vh + (size_t)(kt + vhalf * 32) * HD + vd;
        #pragma unroll
        for (int kk = 0; kk < 32; ++kk)
            vf[kk] = vb[(size_t)kk * HD];
    };

    // sVT key-permuted layout: row d, col c = ks*16 + quad*4 + dw holds
    //   dw=0: keys 32ks+quad*4+{0,1}   dw=1: keys 32ks+quad*4+{2,3}
    //   dw=2: keys 32ks+16+quad*4+{0,1} dw=3: keys 32ks+16+quad*4+{2,3}
    // so the A-fragment read (b128 at col ks*16+quad*4) matches the
    // B-fragment key order of the lane's own p-values.
    auto write_tiles = [&](int buf) {
        #pragma unroll
        for (int p = 0; p < 8; ++p) {
            uint2 kw;
            kw.x = packbf2(kf[p].f[0], kf[p].f[1]);
            kw.y = packbf2(kf[p].f[2], kf[p].f[3]);
            *(uint2*)(&sK[buf][(trow + 8 * p) * KSTR + 4 * dblk]) = kw;
        }
        unsigned* row = &sVT[buf][vd * VSTR + vhalf * 16];
        #pragma unroll
        for (int j = 0; j < 4; ++j) {     // j = quad group
            union { uint4 q; unsigned u[4]; } w;
            w.u[0] = packbf2(vf[4*j],          vf[4*j + 1]);
            w.u[1] = packbf2(vf[4*j + 2],      vf[4*j + 3]);
            w.u[2] = packbf2(vf[16 + 4*j],     vf[16 + 4*j + 1]);
            w.u[3] = packbf2(vf[16 + 4*j + 2], vf[16 + 4*j + 3]);
            *(uint4*)(&row[4*j]) = w.q;
        }
    };

    issue_loads(k_begin);

    for (int it = 0; it < ntiles; ++it) {
        const int kt  = k_begin + it * BC;
        const int buf = it & 1;

        write_tiles(buf);
        __syncthreads();                         // one barrier per tile

        if (it + 1 < ntiles) issue_loads(kt + BC);

        // ---- S^T = K Q^T (skip fully-masked 16-key blocks) ----
        // sc[ct][r] = S[qlane][kt + ct*16 + quad*4 + r]
        floatx4 sc[4];
        __builtin_amdgcn_s_setprio(1);
        #pragma unroll
        for (int ct = 0; ct < 4; ++ct) {
            if (kt + ct * 16 <= qw + 15) {       // wave-uniform
                floatx4 c = (floatx4){0.f, 0.f, 0.f, 0.f};
                #pragma unroll
                for (int ks = 0; ks < 4; ++ks) {
                    short8 a = *(const short8*)(&sK[buf][(ct * 16 + l16) * KSTR + ks * 32 + quad * 8]);
                    c = __builtin_amdgcn_mfma_f32_16x16x32_bf16(a, aq[ks], c, 0, 0, 0);
                }
                sc[ct] = c;
            } else {
                sc[ct] = (floatx4){-1e30f, -1e30f, -1e30f, -1e30f};
            }
        }
        __builtin_amdgcn_s_setprio(0);

        // ---- mask + scale ----
        #pragma unroll
        for (int ct = 0; ct < 4; ++ct) {
            if (kt + ct * 16 <= qw + 15) {
                #pragma unroll
                for (int r = 0; r < 4; ++r) {
                    const int key = kt + ct * 16 + quad * 4 + r;
                    const bool valid = (key <= qlane) && (key >= ds_lane);
                    float s = sc[ct][r] * sl;
                    sc[ct][r] = valid ? s : -1e30f;
                }
            }
        }

        // ---- online softmax: in-lane tree + 2 shfl ----
        float mx0 = fmaxf(fmaxf(sc[0][0], sc[0][1]), fmaxf(sc[0][2], sc[0][3]));
        float mx1 = fmaxf(fmaxf(sc[1][0], sc[1][1]), fmaxf(sc[1][2], sc[1][3]));
        float mx2 = fmaxf(fmaxf(sc[2][0], sc[2][1]), fmaxf(sc[2][2], sc[2][3]));
        float mx3 = fmaxf(fmaxf(sc[3][0], sc[3][1]), fmaxf(sc[3][2], sc[3][3]));
        float mx  = fmaxf(fmaxf(mx0, mx1), fmaxf(mx2, mx3));
        mx = fmaxf(mx, __shfl_xor(mx, 16, 64));
        mx = fmaxf(mx, __shfl_xor(mx, 32, 64));

        const float mnew = fmaxf(m_r, mx);
        const float al   = exp2f(m_r - mnew);
        m_r = mnew;

        float s0 = 0.f, s1 = 0.f, s2 = 0.f, s3 = 0.f;
        #pragma unroll
        for (int ct = 0; ct < 4; ++ct) {
            float p0 = exp2f(sc[ct][0] - m_r);
            float p1 = exp2f(sc[ct][1] - m_r);
            float p2 = exp2f(sc[ct][2] - m_r);
            float p3 = exp2f(sc[ct][3] - m_r);
            sc[ct][0] = p0; sc[ct][1] = p1; sc[ct][2] = p2; sc[ct][3] = p3;
            s0 += p0; s1 += p1; s2 += p2; s3 += p3;
        }
        l_r = l_r * al + ((s0 + s1) + (s2 + s3));
        #pragma unroll
        for (int dt = 0; dt < 8; ++dt) {
            #pragma unroll
            for (int r = 0; r < 4; ++r)
                oacc[dt][r] *= al;
        }

        // ---- O^T += V^T P^T (P stays in registers; skip masked halves) ----
        __builtin_amdgcn_s_setprio(1);
        #pragma unroll
        for (int ks = 0; ks < 2; ++ks) {
            if (kt + ks * 32 <= qw + 15) {       // wave-uniform
                union { unsigned u[4]; short8 s; } pu;   // B-frag = own p-values
                pu.u[0] = packbf2(sc[2*ks][0],   sc[2*ks][1]);
                pu.u[1] = packbf2(sc[2*ks][2],   sc[2*ks][3]);
                pu.u[2] = packbf2(sc[2*ks+1][0], sc[2*ks+1][1]);
                pu.u[3] = packbf2(sc[2*ks+1][2], sc[2*ks+1][3]);
                #pragma unroll
                for (int dt = 0; dt < 8; ++dt) {
                    union { uint4 q; short8 s; } cv;
                    cv.q = *(const uint4*)(&sVT[buf][(dt * 16 + l16) * VSTR + ks * 16 + quad * 4]);
                    oacc[dt] = __builtin_amdgcn_mfma_f32_16x16x32_bf16(cv.s, pu.s, oacc[dt], 0, 0, 0);
                }
            }
        }
        __builtin_amdgcn_s_setprio(0);
    }

    // ---- epilogue: reduce l over quads, float4 stores ----
    l_r += __shfl_xor(l_r, 16, 64);
    l_r += __shfl_xor(l_r, 32, 64);
    const float inv = 1.0f / l_r;
    float* op = Oh + (size_t)qlane * HD + quad * 4;
    #pragma unroll
    for (int dt = 0; dt < 8; ++dt) {
        float4 st;
        st.x = oacc[dt][0] * inv;
        st.y = oacc[dt][1] * inv;
        st.z = oacc[dt][2] * inv;
        st.w = oacc[dt][3] * inv;
        *(float4*)(op + dt * 16) = st;
    }
}

extern "C" void kernel_launch(void* const* d_in, const int* in_sizes, int n_in,
                              void* d_out, int out_size, void* d_ws, size_t ws_size,
                              hipStream_t stream) {
    const float* q = (const float*)d_in[0];
    const float* k = (const float*)d_in[1];
    const float* v = (const float*)d_in[2];
    const int* cu = (const int*)d_in[3];
    const int n_cu = in_sizes[3];
    const int H = 8;
    const int S = in_sizes[0] / (H * HD);   // B=1
    float* out = (float*)d_out;

    dim3 grid(H * (S / BR));   // 512 blocks
    dim3 block(256);
    fa_fwd<<<grid, block, 0, stream>>>(q, k, v, cu, n_cu, out, S);
}